// Round 10
// baseline (329.446 us; speedup 1.0000x reference)
//
#include <hip/hip_runtime.h>
#include <hip/hip_bf16.h>
#include <stdint.h>

#define NN 4096
#define H4 4

typedef __hip_bfloat16 bf16;
typedef unsigned short ushort_t;
typedef unsigned long long ull_t;
typedef __attribute__((ext_vector_type(4))) float f32x4;
typedef __attribute__((ext_vector_type(8))) short s16x8;

__device__ __forceinline__ ushort_t f2bf(float f) {
  unsigned u = __float_as_uint(f);
  return (ushort_t)((u + 0x7fff + ((u >> 16) & 1)) >> 16);
}
__device__ __forceinline__ float bf2f(ushort_t h) {
  return __uint_as_float((unsigned)h << 16);
}
__device__ __forceinline__ short2 pkbf(float a, float b) {
  union { __hip_bfloat162 h; short2 s; } u;
  u.h = __float22bfloat162_rn(make_float2(a, b));
  return u.s;
}
__device__ __forceinline__ s16x8 as_s16x8(uint4 v) {
  union { uint4 u; s16x8 s; } c; c.u = v; return c.s;
}

// ---------------- adj -> 64-bit row masks ----------------
__global__ __launch_bounds__(256) void k_mask(const int* __restrict__ adj,
                                              ull_t* __restrict__ mask) {
  int row = blockIdx.x, tid = threadIdx.x;
  int lane = tid & 63, wv = tid >> 6;
  const int* arow = adj + (size_t)row * NN;
  for (int c = 0; c < NN; c += 256) {
    int col = c + wv * 64 + lane;
    ull_t b = __ballot(arow[col] != 0);
    if (lane == 0) mask[row * 64 + (c >> 6) + wv] = b;
  }
}

// ---------------- tiled GEMM (fp32 VALU; only gemm3 x2@W2 uses it) ----------------
__global__ __launch_bounds__(256) void k_gemm(const float* __restrict__ A,
                                              const float* __restrict__ B,
                                              const float* __restrict__ bias,
                                              float* __restrict__ C, int M, int K, int Nc) {
  __shared__ float As[16][68];
  __shared__ float Bs[16][68];
  int tid = threadIdx.x;
  int tx = tid & 15, ty = tid >> 4;
  int mBase = blockIdx.y * 64, nBase = blockIdx.x * 64;
  float acc[4][4] = {};
  for (int k0 = 0; k0 < K; k0 += 16) {
#pragma unroll
    for (int l = 0; l < 4; ++l) {
      int idx = l * 256 + tid;
      int m = idx >> 4, k = idx & 15;
      As[k][m] = A[(size_t)(mBase + m) * K + (k0 + k)];
    }
#pragma unroll
    for (int l = 0; l < 4; ++l) {
      int idx = l * 256 + tid;
      int k = idx >> 6, n = idx & 63;
      int gn = nBase + n;
      Bs[k][n] = (gn < Nc) ? B[(size_t)(k0 + k) * Nc + gn] : 0.f;
    }
    __syncthreads();
#pragma unroll
    for (int k = 0; k < 16; ++k) {
      float4 a = *(const float4*)&As[k][ty * 4];
      float4 b = *(const float4*)&Bs[k][tx * 4];
      float av[4] = {a.x, a.y, a.z, a.w};
      float bv[4] = {b.x, b.y, b.z, b.w};
#pragma unroll
      for (int r = 0; r < 4; ++r)
#pragma unroll
        for (int c = 0; c < 4; ++c) acc[r][c] += av[r] * bv[c];
    }
    __syncthreads();
  }
#pragma unroll
  for (int r = 0; r < 4; ++r) {
    int gm = mBase + ty * 4 + r;
#pragma unroll
    for (int c = 0; c < 4; ++c) {
      int gn = nBase + tx * 4 + c;
      if (gn < Nc) {
        float v = acc[r][c];
        if (bias) v += bias[gn];
        C[(size_t)gm * Nc + gn] = v;
      }
    }
  }
}

// ---------------- merged parameter packing (x, W1, lw1, lw2) ----------------
#define APLANE (4096 * 512)
template <int KK, int NC>
__device__ __forceinline__ void packW_dev(const float* __restrict__ W,
                                          ushort_t* __restrict__ pk, int tau, int lane) {
  constexpr int KS = KK / 32;
  constexpr int T = (NC / 16) * KS;
  constexpr int PL = T * 512;
  if (tau >= T) return;
  int q = lane >> 4, nn = lane & 15;
  int ct = tau / KS, ks = tau % KS;
  ushort_t hi[8], lo[8];
#pragma unroll
  for (int u = 0; u < 8; ++u) {
    float v = W[(size_t)(ks * 32 + q * 8 + u) * NC + ct * 16 + nn];
    hi[u] = f2bf(v);
    lo[u] = f2bf(v - bf2f(hi[u]));
  }
  size_t idx = ((size_t)(ct * KS + ks) * 64 + lane) * 8;
  *(uint4*)&pk[idx] = *(uint4*)hi;
  *(uint4*)&pk[PL + idx] = *(uint4*)lo;
}

__global__ __launch_bounds__(256) void k_packP(const float* __restrict__ x,
                                               const float* __restrict__ W1,
                                               const float* __restrict__ lw1,
                                               const float* __restrict__ lw2,
                                               ushort_t* __restrict__ pkA,
                                               ushort_t* __restrict__ pkW1,
                                               ushort_t* __restrict__ pkLW1,
                                               ushort_t* __restrict__ pkLW2) {
  int b = blockIdx.x, t = threadIdx.x;
  int w = t >> 6, lane = t & 63;
  if (b < 1024) {  // packA: x[4096][512] -> A-tiles hi/lo
    int q = lane >> 4, nn = lane & 15;
    int tau = b * 4 + w;
    int mt = tau >> 4, ks = tau & 15;
    const float* src = &x[(size_t)(mt * 16 + nn) * 512 + ks * 32 + q * 8];
    float4 v0 = *(const float4*)src;
    float4 v1 = *(const float4*)(src + 4);
    float vv[8] = {v0.x, v0.y, v0.z, v0.w, v1.x, v1.y, v1.z, v1.w};
    ushort_t hi[8], lo[8];
#pragma unroll
    for (int u = 0; u < 8; ++u) {
      hi[u] = f2bf(vv[u]);
      lo[u] = f2bf(vv[u] - bf2f(hi[u]));
    }
    size_t idx = ((size_t)(mt * 16 + ks) * 64 + lane) * 8;
    *(uint4*)&pkA[idx] = *(uint4*)hi;
    *(uint4*)&pkA[APLANE + idx] = *(uint4*)lo;
  } else if (b < 1152) {
    packW_dev<512, 512>(W1, pkW1, (b - 1024) * 4 + w, lane);
  } else if (b < 1168) {
    packW_dev<512, 64>(lw1, pkLW1, (b - 1152) * 4 + w, lane);
  } else {
    packW_dev<128, 16>(lw2, pkLW2, (b - 1168) * 4 + w, lane);
  }
}

// ---------------- h1 = x @ W1 via split-bf16 MFMA (hi*hi + hi*lo + lo*hi) --------
__global__ __launch_bounds__(256, 1) void k_mm1(const uint4* __restrict__ pkA,
                                                const uint4* __restrict__ pkW,
                                                float* __restrict__ h1) {
  constexpr int APL4 = APLANE / 8;
  constexpr int WPL4 = (512 / 16) * (512 / 32) * 64;
  int t = threadIdx.x;
  int w = t >> 6, lane = t & 63;
  int q = lane >> 4, nn = lane & 15;
  int mt0 = blockIdx.x * 4 + (w & 1) * 2;
  int ct0 = blockIdx.y * 8 + (w >> 1) * 4;
  f32x4 acc[2][4];
#pragma unroll
  for (int rt = 0; rt < 2; ++rt)
#pragma unroll
    for (int c = 0; c < 4; ++c)
#pragma unroll
      for (int k = 0; k < 4; ++k) acc[rt][c][k] = 0.f;
#pragma unroll
  for (int ks = 0; ks < 16; ++ks) {
    int ia0 = (mt0 * 16 + ks) * 64 + lane;
    int ia1 = ((mt0 + 1) * 16 + ks) * 64 + lane;
    uint4 ah0 = pkA[ia0], ah1 = pkA[ia1];
    uint4 al0 = pkA[APL4 + ia0], al1 = pkA[APL4 + ia1];
    uint4 bh[4], bl[4];
#pragma unroll
    for (int c = 0; c < 4; ++c) {
      int ib = ((ct0 + c) * 16 + ks) * 64 + lane;
      bh[c] = pkW[ib];
      bl[c] = pkW[WPL4 + ib];
    }
#pragma unroll
    for (int c = 0; c < 4; ++c) {
      acc[0][c] = __builtin_amdgcn_mfma_f32_16x16x32_bf16(as_s16x8(ah0), as_s16x8(bh[c]), acc[0][c], 0, 0, 0);
      acc[0][c] = __builtin_amdgcn_mfma_f32_16x16x32_bf16(as_s16x8(ah0), as_s16x8(bl[c]), acc[0][c], 0, 0, 0);
      acc[0][c] = __builtin_amdgcn_mfma_f32_16x16x32_bf16(as_s16x8(al0), as_s16x8(bh[c]), acc[0][c], 0, 0, 0);
      acc[1][c] = __builtin_amdgcn_mfma_f32_16x16x32_bf16(as_s16x8(ah1), as_s16x8(bh[c]), acc[1][c], 0, 0, 0);
      acc[1][c] = __builtin_amdgcn_mfma_f32_16x16x32_bf16(as_s16x8(ah1), as_s16x8(bl[c]), acc[1][c], 0, 0, 0);
      acc[1][c] = __builtin_amdgcn_mfma_f32_16x16x32_bf16(as_s16x8(al1), as_s16x8(bh[c]), acc[1][c], 0, 0, 0);
    }
  }
  int rowB = blockIdx.x * 64 + (w & 1) * 32;
#pragma unroll
  for (int rt = 0; rt < 2; ++rt)
#pragma unroll
    for (int c = 0; c < 4; ++c)
#pragma unroll
      for (int reg = 0; reg < 4; ++reg) {
        int gi = rowB + rt * 16 + q * 4 + reg;
        h1[(size_t)gi * 512 + (ct0 + c) * 16 + nn] = acc[rt][c][reg];
      }
}

// ---------------- pack h[N][H4*F] f32 into MFMA B-fragment tiles (bf16) --------
template <int F, int TB>
__global__ __launch_bounds__(TB) void k_pack(const float* __restrict__ h,
                                             ushort_t* __restrict__ pk) {
  constexpr int CTW = TB / 64;
  int t = threadIdx.x;
  int lane = t & 63, ctw = t >> 6;
  int q = lane >> 4, nn = lane & 15;
  int ks = blockIdx.x, hd = blockIdx.y;
#pragma unroll
  for (int ct = ctw; ct < F / 16; ct += CTW) {
    ushort_t v[8];
#pragma unroll
    for (int u = 0; u < 8; ++u)
      v[u] = f2bf(h[(size_t)(ks * 32 + q * 8 + u) * (H4 * F) + hd * F + ct * 16 + nn]);
    *(uint4*)&pk[((((size_t)hd * (F / 16) + ct) * (NN / 32) + ks) * 64 + lane) * 8] =
        *(uint4*)v;
  }
}

// ---------------- attention scores -> factorized-exp tables ----------------
// E1=exp(es), E2=exp(0.2 es), T=exp(-es), D1=exp(ed), D2=exp(0.2 ed).
// Then u_ij = mask ? (D1_j > T_i ? E1_i*D1_j : E2_i*D2_j) : 0  ==  exp(lrelu(es+ed)).
template <int F>
__global__ __launch_bounds__(256) void k_scores(const float* __restrict__ h,
                                                const float* __restrict__ a_s,
                                                const float* __restrict__ a_d,
                                                float* __restrict__ Tt, float* __restrict__ E1,
                                                float* __restrict__ E2, float* __restrict__ D1,
                                                float* __restrict__ D2) {
  int idx = blockIdx.x * 256 + threadIdx.x;
  if (idx >= NN * H4) return;
  int n = idx >> 2, hd = idx & 3;
  const float* hp = h + (size_t)n * (H4 * F) + hd * F;
  const float* sp = a_s + hd * F;
  const float* dp = a_d + hd * F;
  float ss = 0.f, sd = 0.f;
#pragma unroll 4
  for (int f = 0; f < F; ++f) {
    float v = hp[f];
    ss += v * sp[f];
    sd += v * dp[f];
  }
  ss = fminf(fmaxf(ss, -30.f), 30.f);  // insurance clamp (never binds; consistent num/den)
  sd = fminf(fmaxf(sd, -30.f), 30.f);
  int o = hd * NN + n;
  Tt[o] = __expf(-ss);
  E1[o] = __expf(ss);
  E2[o] = __expf(0.2f * ss);
  D1[o] = __expf(sd);
  D2[o] = __expf(0.2f * sd);
}

// ---------------- MFMA aggregation, factorized-exp weights, fused normalize ------
// Wave = one 16-row tile x all F cols of one head, over a j-quarter; block = 4 waves
// (4 j-quarters, same rows); grid (256,H4) = 1024 blocks -> 4 blocks/CU.
// A-frag built in-lane with NO transcendentals (tables E1/E2/T per-row, D1/D2 per-j).
// Row-sum rs accumulated in fp32 alongside; 2-barrier LDS reduce; epilogue divides
// and writes packed MFMA-A tiles for the next linear layer (OUTM=1: hi/lo planes).
__device__ __forceinline__ s16x8 build_af(float E1i, float E2i, float Ti, unsigned byt,
                                          float4 d1a, float4 d1b, float4 d2a, float4 d2b,
                                          float& rs) {
  float d1[8] = {d1a.x, d1a.y, d1a.z, d1a.w, d1b.x, d1b.y, d1b.z, d1b.w};
  float d2[8] = {d2a.x, d2a.y, d2a.z, d2a.w, d2b.x, d2b.y, d2b.z, d2b.w};
  union { s16x8 v; short2 p[4]; } A;
#pragma unroll
  for (int tp = 0; tp < 4; ++tp) {
    int k0 = 2 * tp, k1 = 2 * tp + 1;
    bool p0 = d1[k0] > Ti;
    float u0 = (p0 ? E1i : E2i) * (p0 ? d1[k0] : d2[k0]);
    u0 = (byt & (1u << k0)) ? u0 : 0.f;
    bool p1 = d1[k1] > Ti;
    float u1 = (p1 ? E1i : E2i) * (p1 ? d1[k1] : d2[k1]);
    u1 = (byt & (1u << k1)) ? u1 : 0.f;
    rs += u0 + u1;
    A.p[tp] = pkbf(u0, u1);
  }
  return A.v;
}

template <int F, int OUTM>
__global__ __launch_bounds__(256, 4) void k_agg_mfma(
    const uint4* __restrict__ pk, const float* __restrict__ Tt,
    const float* __restrict__ E1, const float* __restrict__ E2,
    const float* __restrict__ D1, const float* __restrict__ D2,
    const ull_t* __restrict__ mask, ushort_t* __restrict__ pkOut) {
  constexpr int CT = F / 16;
  constexpr int KSO = (H4 * F) / 32;
  constexpr int OPL = NN * H4 * F;
  __shared__ float red[2 * 16 * F];
  __shared__ float rsred[16 * 4];
  int t = threadIdx.x;
  int w = t >> 6, lane = t & 63;
  int q = lane >> 4, nn = lane & 15;
  int hd = blockIdx.y;
  int rowBase = blockIdx.x * 16;
  int jBase = w * (NN / 4);
  int ia = rowBase + nn;
  float E1i = E1[hd * NN + ia];
  float E2i = E2[hd * NN + ia];
  float Ti = Tt[hd * NN + ia];
  const ull_t* mkp = mask + (size_t)ia * 64;
  const float* d1h = D1 + hd * NN;
  const float* d2h = D2 + hd * NN;

  f32x4 acc[CT];
#pragma unroll
  for (int cc = 0; cc < CT; ++cc)
#pragma unroll
    for (int k = 0; k < 4; ++k) acc[cc][k] = 0.f;
  float rs = 0.f;

  for (int jc = 0; jc < NN / 4 / 64; ++jc) {
    int j0 = jBase + jc * 64;
    int ks0 = j0 >> 5;
    ull_t mk = mkp[j0 >> 6];
    float4 d1a = *(const float4*)&d1h[j0 + q * 8];
    float4 d1b = *(const float4*)&d1h[j0 + q * 8 + 4];
    float4 d2a = *(const float4*)&d2h[j0 + q * 8];
    float4 d2b = *(const float4*)&d2h[j0 + q * 8 + 4];
    float4 d1c = *(const float4*)&d1h[j0 + 32 + q * 8];
    float4 d1d = *(const float4*)&d1h[j0 + 32 + q * 8 + 4];
    float4 d2c = *(const float4*)&d2h[j0 + 32 + q * 8];
    float4 d2d = *(const float4*)&d2h[j0 + 32 + q * 8 + 4];
    s16x8 a0 = build_af(E1i, E2i, Ti, (unsigned)(mk >> (q * 8)) & 0xffu, d1a, d1b, d2a, d2b, rs);
    s16x8 a1 = build_af(E1i, E2i, Ti, (unsigned)(mk >> (32 + q * 8)) & 0xffu, d1c, d1d, d2c, d2d, rs);
    uint4 bv[CT];
#pragma unroll
    for (int cc = 0; cc < CT; ++cc)
      bv[cc] = pk[(size_t)((hd * CT + cc) * (NN / 32) + ks0) * 64 + lane];
#pragma unroll
    for (int cc = 0; cc < CT; ++cc)
      acc[cc] = __builtin_amdgcn_mfma_f32_16x16x32_bf16(a0, as_s16x8(bv[cc]), acc[cc], 0, 0, 0);
#pragma unroll
    for (int cc = 0; cc < CT; ++cc)
      bv[cc] = pk[(size_t)((hd * CT + cc) * (NN / 32) + ks0 + 1) * 64 + lane];
#pragma unroll
    for (int cc = 0; cc < CT; ++cc)
      acc[cc] = __builtin_amdgcn_mfma_f32_16x16x32_bf16(a1, as_s16x8(bv[cc]), acc[cc], 0, 0, 0);
  }

  // rs: reduce across q-quads (lanes sharing nn), stash per wave
  rs += __shfl_xor(rs, 16, 64);
  rs += __shfl_xor(rs, 32, 64);
  if (q == 0) rsred[nn * 4 + w] = rs;

  // acc: 2-barrier cross-wave reduce (w1->r0, w3->r1; w0+=r0, w2+=r1->r1; w0+=r1)
#define IDX(cc, reg) (((q * 4 + reg) * F) + cc * 16 + nn)
  if (w == 1) {
#pragma unroll
    for (int cc = 0; cc < CT; ++cc)
#pragma unroll
      for (int reg = 0; reg < 4; ++reg) red[IDX(cc, reg)] = acc[cc][reg];
  }
  if (w == 3) {
#pragma unroll
    for (int cc = 0; cc < CT; ++cc)
#pragma unroll
      for (int reg = 0; reg < 4; ++reg) red[16 * F + IDX(cc, reg)] = acc[cc][reg];
  }
  __syncthreads();
  if (w == 0) {
#pragma unroll
    for (int cc = 0; cc < CT; ++cc)
#pragma unroll
      for (int reg = 0; reg < 4; ++reg) acc[cc][reg] += red[IDX(cc, reg)];
  }
  if (w == 2) {
#pragma unroll
    for (int cc = 0; cc < CT; ++cc)
#pragma unroll
      for (int reg = 0; reg < 4; ++reg) {
        acc[cc][reg] += red[16 * F + IDX(cc, reg)];
        red[16 * F + IDX(cc, reg)] = acc[cc][reg];
      }
  }
  __syncthreads();
  if (w == 0) {
    float rinv[4];
#pragma unroll
    for (int reg = 0; reg < 4; ++reg) {
      float4 rv = *(float4*)&rsred[(q * 4 + reg) * 4];
      float s = (rv.x + rv.y) + (rv.z + rv.w);
      rinv[reg] = (s > 0.f) ? 1.f / s : 0.f;
    }
#pragma unroll
    for (int cc = 0; cc < CT; ++cc)
#pragma unroll
      for (int reg = 0; reg < 4; ++reg) {
        float v = (acc[cc][reg] + red[16 * F + IDX(cc, reg)]) * rinv[reg];
        int gi = rowBase + q * 4 + reg;
        int c = hd * F + cc * 16 + nn;
        int mt = gi >> 4, rowin = gi & 15;
        int ks = c >> 5, qp = (c >> 3) & 3, u = c & 7;
        size_t idx = (((size_t)mt * KSO + ks) * 64 + qp * 16 + rowin) * 8 + u;
        ushort_t hi = f2bf(v);
        pkOut[idx] = hi;
        if (OUTM == 1) pkOut[OPL + idx] = f2bf(v - bf2f(hi));
      }
  }
#undef IDX
}

// ---------------- y1 = pkX1(bf16) @ lw1(hi/lo) + lb1, MFMA, K-split x2 ----------------
__global__ __launch_bounds__(256) void k_mm2(const uint4* __restrict__ pkX,
                                             const uint4* __restrict__ pkW,
                                             const float* __restrict__ bias,
                                             float* __restrict__ y) {
  constexpr int WPL4 = 4 * 16 * 64;
  __shared__ float red[2 * 16 * 64];
  int t = threadIdx.x;
  int w = t >> 6, lane = t & 63;
  int q = lane >> 4, nn = lane & 15;
  int mt = blockIdx.x * 2 + (w & 1);
  int kh = w >> 1;
  f32x4 acc[4];
#pragma unroll
  for (int c = 0; c < 4; ++c)
#pragma unroll
    for (int k = 0; k < 4; ++k) acc[c][k] = 0.f;
#pragma unroll
  for (int k8 = 0; k8 < 8; ++k8) {
    int ks = kh * 8 + k8;
    uint4 a = pkX[(mt * 16 + ks) * 64 + lane];
#pragma unroll
    for (int c = 0; c < 4; ++c) {
      uint4 bh = pkW[(c * 16 + ks) * 64 + lane];
      uint4 bl = pkW[WPL4 + (c * 16 + ks) * 64 + lane];
      acc[c] = __builtin_amdgcn_mfma_f32_16x16x32_bf16(as_s16x8(a), as_s16x8(bh), acc[c], 0, 0, 0);
      acc[c] = __builtin_amdgcn_mfma_f32_16x16x32_bf16(as_s16x8(a), as_s16x8(bl), acc[c], 0, 0, 0);
    }
  }
  int base = (w & 1) * 1024;
  if (kh == 1) {
#pragma unroll
    for (int c = 0; c < 4; ++c)
#pragma unroll
      for (int reg = 0; reg < 4; ++reg)
        red[base + (q * 4 + reg) * 64 + c * 16 + nn] = acc[c][reg];
  }
  __syncthreads();
  if (kh == 0) {
#pragma unroll
    for (int c = 0; c < 4; ++c)
#pragma unroll
      for (int reg = 0; reg < 4; ++reg) {
        float v = acc[c][reg] + red[base + (q * 4 + reg) * 64 + c * 16 + nn] + bias[c * 16 + nn];
        y[(size_t)(mt * 16 + q * 4 + reg) * 64 + c * 16 + nn] = v;
      }
  }
}

// ---------------- y2 = pkX3(hi/lo) @ lw2(hi/lo) + lb2, MFMA ----------------
__global__ __launch_bounds__(256) void k_mm4(const uint4* __restrict__ pkX,
                                             const uint4* __restrict__ pkW,
                                             const float* __restrict__ bias,
                                             float* __restrict__ y) {
  constexpr int XPL4 = 256 * 4 * 64;
  constexpr int WPL4 = 1 * 4 * 64;
  int t = threadIdx.x;
  int w = t >> 6, lane = t & 63;
  int q = lane >> 4, nn = lane & 15;
  int mt = blockIdx.x * 4 + w;
  f32x4 acc;
#pragma unroll
  for (int k = 0; k < 4; ++k) acc[k] = 0.f;
#pragma unroll
  for (int ks = 0; ks < 4; ++ks) {
    uint4 ah = pkX[(mt * 4 + ks) * 64 + lane];
    uint4 al = pkX[XPL4 + (mt * 4 + ks) * 64 + lane];
    uint4 bh = pkW[ks * 64 + lane];
    uint4 bl = pkW[WPL4 + ks * 64 + lane];
    acc = __builtin_amdgcn_mfma_f32_16x16x32_bf16(as_s16x8(ah), as_s16x8(bh), acc, 0, 0, 0);
    acc = __builtin_amdgcn_mfma_f32_16x16x32_bf16(as_s16x8(ah), as_s16x8(bl), acc, 0, 0, 0);
    acc = __builtin_amdgcn_mfma_f32_16x16x32_bf16(as_s16x8(al), as_s16x8(bh), acc, 0, 0, 0);
  }
  float b = bias[nn];
#pragma unroll
  for (int reg = 0; reg < 4; ++reg)
    y[(size_t)(mt * 16 + q * 4 + reg) * 16 + nn] = acc[reg] + b;
}

// ---------------- fused per-column BN stats + BN + ELU ----------------
__global__ __launch_bounds__(256) void k_bn_col(const float* __restrict__ y,
                                                const float* __restrict__ gamma,
                                                const float* __restrict__ beta,
                                                float* __restrict__ o, int C) {
  int c = blockIdx.x, tid = threadIdx.x;
  float s = 0.f, s2 = 0.f;
  for (int r = tid; r < NN; r += 256) {
    float v = y[(size_t)r * C + c];
    s += v;
    s2 += v * v;
  }
  __shared__ float sh[256], sh2[256];
  __shared__ float smu, srs;
  sh[tid] = s; sh2[tid] = s2;
  __syncthreads();
  for (int off = 128; off; off >>= 1) {
    if (tid < off) { sh[tid] += sh[tid + off]; sh2[tid] += sh2[tid + off]; }
    __syncthreads();
  }
  if (tid == 0) {
    float mu = sh[0] * (1.f / NN);
    float var = sh2[0] * (1.f / NN) - mu * mu;
    smu = mu;
    srs = rsqrtf(fmaxf(var, 0.f) + 1e-5f);
  }
  __syncthreads();
  float mu = smu, rstd = srs, g = gamma[c], b = beta[c];
  for (int r = tid; r < NN; r += 256) {
    float v = (y[(size_t)r * C + c] - mu) * rstd * g + b;
    v = v > 0.f ? v : (__expf(v) - 1.f);
    o[(size_t)r * C + c] = v;
  }
}

extern "C" void kernel_launch(void* const* d_in, const int* in_sizes, int n_in,
                              void* d_out, int out_size, void* d_ws, size_t ws_size,
                              hipStream_t stream) {
  (void)in_sizes; (void)n_in; (void)out_size; (void)ws_size;
  const float* x   = (const float*)d_in[0];
  const int*   adj = (const int*)d_in[1];
  const float* W1  = (const float*)d_in[2];
  const float* a1s = (const float*)d_in[3];
  const float* a1d = (const float*)d_in[4];
  const float* lw1 = (const float*)d_in[5];
  const float* lb1 = (const float*)d_in[6];
  const float* g1  = (const float*)d_in[7];
  const float* be1 = (const float*)d_in[8];
  const float* W2  = (const float*)d_in[9];
  const float* a2s = (const float*)d_in[10];
  const float* a2d = (const float*)d_in[11];
  const float* lw2 = (const float*)d_in[12];
  const float* lb2 = (const float*)d_in[13];
  const float* g2  = (const float*)d_in[14];
  const float* be2 = (const float*)d_in[15];
  float* out = (float*)d_out;

  // ---- workspace: LINEAR layout, no overlays (~38 MB of >=268 MB) ----
  char* w = (char*)d_ws;
  const size_t MB = 1u << 20;
  ull_t*    mask  = (ull_t*)(w + 0);              // 2 MB
  ushort_t* pkA   = (ushort_t*)(w + 2 * MB);      // 8 MB
  ushort_t* pkW1  = (ushort_t*)(w + 10 * MB);     // 1 MB
  float*    h1    = (float*)(w + 11 * MB);        // 8 MB
  ushort_t* pk1   = (ushort_t*)(w + 19 * MB);     // 4 MB
  float*    T1    = (float*)(w + 23 * MB);        // 5 x 64 KB
  float*    E1a   = T1 + 16384;
  float*    E2a   = E1a + 16384;
  float*    D1a   = E2a + 16384;
  float*    D2a   = D1a + 16384;
  ushort_t* pkX1  = (ushort_t*)(w + 24 * MB);     // 4 MB
  ushort_t* pkLW1 = (ushort_t*)(w + 28 * MB);     // 128 KB
  float*    y1    = (float*)(w + 29 * MB);        // 1 MB
  float*    x2    = (float*)(w + 30 * MB);        // 1 MB
  float*    h2    = (float*)(w + 31 * MB);        // 2 MB
  ushort_t* pk2   = (ushort_t*)(w + 33 * MB);     // 1 MB
  float*    T2    = (float*)(w + 34 * MB);        // 5 x 64 KB
  float*    E1b   = T2 + 16384;
  float*    E2b   = E1b + 16384;
  float*    D1b   = E2b + 16384;
  float*    D2b   = D1b + 16384;
  ushort_t* pkX3  = (ushort_t*)(w + 35 * MB);     // 2 MB
  ushort_t* pkLW2 = (ushort_t*)(w + 37 * MB);     // 8 KB
  float*    y2    = (float*)(w + 37 * MB + 131072);  // 256 KB

  k_mask<<<NN, 256, 0, stream>>>(adj, mask);
  k_packP<<<1169, 256, 0, stream>>>(x, W1, lw1, lw2, pkA, pkW1, pkLW1, pkLW2);

  // ---- layer 1 GAT ----
  k_mm1<<<dim3(64, 4), 256, 0, stream>>>((const uint4*)pkA, (const uint4*)pkW1, h1);
  k_pack<128, 256><<<dim3(NN / 32, H4), 256, 0, stream>>>(h1, pk1);
  k_scores<128><<<(NN * H4) / 256, 256, 0, stream>>>(h1, a1s, a1d, T1, E1a, E2a, D1a, D2a);
  k_agg_mfma<128, 0><<<dim3(NN / 16, H4), 256, 0, stream>>>((const uint4*)pk1, T1, E1a, E2a,
                                                            D1a, D2a, mask, pkX1);

  // ---- linear + BN + ELU ----
  k_mm2<<<128, 256, 0, stream>>>((const uint4*)pkX1, (const uint4*)pkLW1, lb1, y1);
  k_bn_col<<<64, 256, 0, stream>>>(y1, g1, be1, x2, 64);

  // ---- layer 2 GAT ----
  k_gemm<<<dim3(2, 64), 256, 0, stream>>>(x2, W2, nullptr, h2, NN, 64, 128);
  k_pack<32, 128><<<dim3(NN / 32, H4), 128, 0, stream>>>(h2, pk2);
  k_scores<32><<<(NN * H4) / 256, 256, 0, stream>>>(h2, a2s, a2d, T2, E1b, E2b, D1b, D2b);
  k_agg_mfma<32, 1><<<dim3(NN / 16, H4), 256, 0, stream>>>((const uint4*)pk2, T2, E1b, E2b,
                                                           D1b, D2b, mask, pkX3);

  // ---- final linear + BN + ELU ----
  k_mm4<<<64, 256, 0, stream>>>((const uint4*)pkX3, (const uint4*)pkLW2, lb2, y2);
  k_bn_col<<<16, 256, 0, stream>>>(y2, g2, be2, out, 16);
}

// Round 11
// 292.663 us; speedup vs baseline: 1.1257x; 1.1257x over previous
//
#include <hip/hip_runtime.h>
#include <hip/hip_bf16.h>
#include <stdint.h>

#define NN 4096
#define H4 4

typedef __hip_bfloat16 bf16;
typedef unsigned short ushort_t;
typedef unsigned long long ull_t;
typedef __attribute__((ext_vector_type(4))) float f32x4;
typedef __attribute__((ext_vector_type(8))) short s16x8;

__device__ __forceinline__ ushort_t f2bf(float f) {
  unsigned u = __float_as_uint(f);
  return (ushort_t)((u + 0x7fff + ((u >> 16) & 1)) >> 16);
}
__device__ __forceinline__ float bf2f(ushort_t h) {
  return __uint_as_float((unsigned)h << 16);
}
__device__ __forceinline__ short2 pkbf(float a, float b) {
  union { __hip_bfloat162 h; short2 s; } u;
  u.h = __float22bfloat162_rn(make_float2(a, b));
  return u.s;
}
__device__ __forceinline__ s16x8 as_s16x8(uint4 v) {
  union { uint4 u; s16x8 s; } c; c.u = v; return c.s;
}

// ---------------- adj -> 64-bit row masks ----------------
__global__ __launch_bounds__(256) void k_mask(const int* __restrict__ adj,
                                              ull_t* __restrict__ mask) {
  int row = blockIdx.x, tid = threadIdx.x;
  int lane = tid & 63, wv = tid >> 6;
  const int* arow = adj + (size_t)row * NN;
  for (int c = 0; c < NN; c += 256) {
    int col = c + wv * 64 + lane;
    ull_t b = __ballot(arow[col] != 0);
    if (lane == 0) mask[row * 64 + (c >> 6) + wv] = b;
  }
}

// ---------------- tiled GEMM (fp32 VALU; only gemm3 x2@W2 uses it) ----------------
__global__ __launch_bounds__(256) void k_gemm(const float* __restrict__ A,
                                              const float* __restrict__ B,
                                              const float* __restrict__ bias,
                                              float* __restrict__ C, int M, int K, int Nc) {
  __shared__ float As[16][68];
  __shared__ float Bs[16][68];
  int tid = threadIdx.x;
  int tx = tid & 15, ty = tid >> 4;
  int mBase = blockIdx.y * 64, nBase = blockIdx.x * 64;
  float acc[4][4] = {};
  for (int k0 = 0; k0 < K; k0 += 16) {
#pragma unroll
    for (int l = 0; l < 4; ++l) {
      int idx = l * 256 + tid;
      int m = idx >> 4, k = idx & 15;
      As[k][m] = A[(size_t)(mBase + m) * K + (k0 + k)];
    }
#pragma unroll
    for (int l = 0; l < 4; ++l) {
      int idx = l * 256 + tid;
      int k = idx >> 6, n = idx & 63;
      int gn = nBase + n;
      Bs[k][n] = (gn < Nc) ? B[(size_t)(k0 + k) * Nc + gn] : 0.f;
    }
    __syncthreads();
#pragma unroll
    for (int k = 0; k < 16; ++k) {
      float4 a = *(const float4*)&As[k][ty * 4];
      float4 b = *(const float4*)&Bs[k][tx * 4];
      float av[4] = {a.x, a.y, a.z, a.w};
      float bv[4] = {b.x, b.y, b.z, b.w};
#pragma unroll
      for (int r = 0; r < 4; ++r)
#pragma unroll
        for (int c = 0; c < 4; ++c) acc[r][c] += av[r] * bv[c];
    }
    __syncthreads();
  }
#pragma unroll
  for (int r = 0; r < 4; ++r) {
    int gm = mBase + ty * 4 + r;
#pragma unroll
    for (int c = 0; c < 4; ++c) {
      int gn = nBase + tx * 4 + c;
      if (gn < Nc) {
        float v = acc[r][c];
        if (bias) v += bias[gn];
        C[(size_t)gm * Nc + gn] = v;
      }
    }
  }
}

// ---------------- merged parameter packing (x, W1, lw1, lw2) ----------------
#define APLANE (4096 * 512)
template <int KK, int NC>
__device__ __forceinline__ void packW_dev(const float* __restrict__ W,
                                          ushort_t* __restrict__ pk, int tau, int lane) {
  constexpr int KS = KK / 32;
  constexpr int T = (NC / 16) * KS;
  constexpr int PL = T * 512;
  if (tau >= T) return;
  int q = lane >> 4, nn = lane & 15;
  int ct = tau / KS, ks = tau % KS;
  ushort_t hi[8], lo[8];
#pragma unroll
  for (int u = 0; u < 8; ++u) {
    float v = W[(size_t)(ks * 32 + q * 8 + u) * NC + ct * 16 + nn];
    hi[u] = f2bf(v);
    lo[u] = f2bf(v - bf2f(hi[u]));
  }
  size_t idx = ((size_t)(ct * KS + ks) * 64 + lane) * 8;
  *(uint4*)&pk[idx] = *(uint4*)hi;
  *(uint4*)&pk[PL + idx] = *(uint4*)lo;
}

__global__ __launch_bounds__(256) void k_packP(const float* __restrict__ x,
                                               const float* __restrict__ W1,
                                               const float* __restrict__ lw1,
                                               const float* __restrict__ lw2,
                                               ushort_t* __restrict__ pkA,
                                               ushort_t* __restrict__ pkW1,
                                               ushort_t* __restrict__ pkLW1,
                                               ushort_t* __restrict__ pkLW2) {
  int b = blockIdx.x, t = threadIdx.x;
  int w = t >> 6, lane = t & 63;
  if (b < 1024) {  // packA: x[4096][512] -> A-tiles hi/lo
    int q = lane >> 4, nn = lane & 15;
    int tau = b * 4 + w;
    int mt = tau >> 4, ks = tau & 15;
    const float* src = &x[(size_t)(mt * 16 + nn) * 512 + ks * 32 + q * 8];
    float4 v0 = *(const float4*)src;
    float4 v1 = *(const float4*)(src + 4);
    float vv[8] = {v0.x, v0.y, v0.z, v0.w, v1.x, v1.y, v1.z, v1.w};
    ushort_t hi[8], lo[8];
#pragma unroll
    for (int u = 0; u < 8; ++u) {
      hi[u] = f2bf(vv[u]);
      lo[u] = f2bf(vv[u] - bf2f(hi[u]));
    }
    size_t idx = ((size_t)(mt * 16 + ks) * 64 + lane) * 8;
    *(uint4*)&pkA[idx] = *(uint4*)hi;
    *(uint4*)&pkA[APLANE + idx] = *(uint4*)lo;
  } else if (b < 1152) {
    packW_dev<512, 512>(W1, pkW1, (b - 1024) * 4 + w, lane);
  } else if (b < 1168) {
    packW_dev<512, 64>(lw1, pkLW1, (b - 1152) * 4 + w, lane);
  } else {
    packW_dev<128, 16>(lw2, pkLW2, (b - 1168) * 4 + w, lane);
  }
}

// ---------------- h1 = x @ W1 via split-bf16 MFMA (hi*hi + hi*lo + lo*hi) --------
__global__ __launch_bounds__(256, 1) void k_mm1(const uint4* __restrict__ pkA,
                                                const uint4* __restrict__ pkW,
                                                float* __restrict__ h1) {
  constexpr int APL4 = APLANE / 8;
  constexpr int WPL4 = (512 / 16) * (512 / 32) * 64;
  int t = threadIdx.x;
  int w = t >> 6, lane = t & 63;
  int q = lane >> 4, nn = lane & 15;
  int mt0 = blockIdx.x * 4 + (w & 1) * 2;
  int ct0 = blockIdx.y * 8 + (w >> 1) * 4;
  f32x4 acc[2][4];
#pragma unroll
  for (int rt = 0; rt < 2; ++rt)
#pragma unroll
    for (int c = 0; c < 4; ++c)
#pragma unroll
      for (int k = 0; k < 4; ++k) acc[rt][c][k] = 0.f;
#pragma unroll
  for (int ks = 0; ks < 16; ++ks) {
    int ia0 = (mt0 * 16 + ks) * 64 + lane;
    int ia1 = ((mt0 + 1) * 16 + ks) * 64 + lane;
    uint4 ah0 = pkA[ia0], ah1 = pkA[ia1];
    uint4 al0 = pkA[APL4 + ia0], al1 = pkA[APL4 + ia1];
    uint4 bh[4], bl[4];
#pragma unroll
    for (int c = 0; c < 4; ++c) {
      int ib = ((ct0 + c) * 16 + ks) * 64 + lane;
      bh[c] = pkW[ib];
      bl[c] = pkW[WPL4 + ib];
    }
#pragma unroll
    for (int c = 0; c < 4; ++c) {
      acc[0][c] = __builtin_amdgcn_mfma_f32_16x16x32_bf16(as_s16x8(ah0), as_s16x8(bh[c]), acc[0][c], 0, 0, 0);
      acc[0][c] = __builtin_amdgcn_mfma_f32_16x16x32_bf16(as_s16x8(ah0), as_s16x8(bl[c]), acc[0][c], 0, 0, 0);
      acc[0][c] = __builtin_amdgcn_mfma_f32_16x16x32_bf16(as_s16x8(al0), as_s16x8(bh[c]), acc[0][c], 0, 0, 0);
      acc[1][c] = __builtin_amdgcn_mfma_f32_16x16x32_bf16(as_s16x8(ah1), as_s16x8(bh[c]), acc[1][c], 0, 0, 0);
      acc[1][c] = __builtin_amdgcn_mfma_f32_16x16x32_bf16(as_s16x8(ah1), as_s16x8(bl[c]), acc[1][c], 0, 0, 0);
      acc[1][c] = __builtin_amdgcn_mfma_f32_16x16x32_bf16(as_s16x8(al1), as_s16x8(bh[c]), acc[1][c], 0, 0, 0);
    }
  }
  int rowB = blockIdx.x * 64 + (w & 1) * 32;
#pragma unroll
  for (int rt = 0; rt < 2; ++rt)
#pragma unroll
    for (int c = 0; c < 4; ++c)
#pragma unroll
      for (int reg = 0; reg < 4; ++reg) {
        int gi = rowB + rt * 16 + q * 4 + reg;
        h1[(size_t)gi * 512 + (ct0 + c) * 16 + nn] = acc[rt][c][reg];
      }
}

// ---------------- pack h[N][H4*F] f32 into MFMA B-fragment tiles (bf16) --------
template <int F, int TB>
__global__ __launch_bounds__(TB) void k_pack(const float* __restrict__ h,
                                             ushort_t* __restrict__ pk) {
  constexpr int CTW = TB / 64;
  int t = threadIdx.x;
  int lane = t & 63, ctw = t >> 6;
  int q = lane >> 4, nn = lane & 15;
  int ks = blockIdx.x, hd = blockIdx.y;
#pragma unroll
  for (int ct = ctw; ct < F / 16; ct += CTW) {
    ushort_t v[8];
#pragma unroll
    for (int u = 0; u < 8; ++u)
      v[u] = f2bf(h[(size_t)(ks * 32 + q * 8 + u) * (H4 * F) + hd * F + ct * 16 + nn]);
    *(uint4*)&pk[((((size_t)hd * (F / 16) + ct) * (NN / 32) + ks) * 64 + lane) * 8] =
        *(uint4*)v;
  }
}

// ---------------- attention scores -> factorized-exp tables ----------------
// E1=exp(es), E2=exp(0.2 es), T=exp(-es), D1=exp(ed), D2=exp(0.2 ed).
// u_ij = mask ? (D1_j > T_i ? E1_i*D1_j : E2_i*D2_j) : 0  ==  exp(lrelu(es+ed)).
template <int F>
__global__ __launch_bounds__(256) void k_scores(const float* __restrict__ h,
                                                const float* __restrict__ a_s,
                                                const float* __restrict__ a_d,
                                                float* __restrict__ Tt, float* __restrict__ E1,
                                                float* __restrict__ E2, float* __restrict__ D1,
                                                float* __restrict__ D2) {
  int idx = blockIdx.x * 256 + threadIdx.x;
  if (idx >= NN * H4) return;
  int n = idx >> 2, hd = idx & 3;
  const float* hp = h + (size_t)n * (H4 * F) + hd * F;
  const float* sp = a_s + hd * F;
  const float* dp = a_d + hd * F;
  float ss = 0.f, sd = 0.f;
#pragma unroll 4
  for (int f = 0; f < F; ++f) {
    float v = hp[f];
    ss += v * sp[f];
    sd += v * dp[f];
  }
  ss = fminf(fmaxf(ss, -30.f), 30.f);
  sd = fminf(fmaxf(sd, -30.f), 30.f);
  int o = hd * NN + n;
  Tt[o] = __expf(-ss);
  E1[o] = __expf(ss);
  E2[o] = __expf(0.2f * ss);
  D1[o] = __expf(sd);
  D2[o] = __expf(0.2f * sd);
}

// ---------------- MFMA aggregation: R9 geometry + factorized weights ----------------
// Wave = 32 rows (2 row-tiles) x all F cols of one head, over a j-quarter.
// Block = 4 waves (4 j-quarters, same rows); grid (128,H4)=512 blocks -> 2/CU.
// A-frags built in-lane, transcendental-free; unnormalized row-sum rs reduced over
// q-quads + waves; epilogue divides and writes packed MFMA-A tiles for next layer.
__device__ __forceinline__ s16x8 build_af(float E1i, float E2i, float Ti, unsigned byt,
                                          float4 d1a, float4 d1b, float4 d2a, float4 d2b,
                                          float& rs) {
  float d1[8] = {d1a.x, d1a.y, d1a.z, d1a.w, d1b.x, d1b.y, d1b.z, d1b.w};
  float d2[8] = {d2a.x, d2a.y, d2a.z, d2a.w, d2b.x, d2b.y, d2b.z, d2b.w};
  union { s16x8 v; short2 p[4]; } A;
#pragma unroll
  for (int tp = 0; tp < 4; ++tp) {
    int k0 = 2 * tp, k1 = 2 * tp + 1;
    bool p0 = d1[k0] > Ti;
    float u0 = (p0 ? E1i : E2i) * (p0 ? d1[k0] : d2[k0]);
    u0 = (byt & (1u << k0)) ? u0 : 0.f;
    bool p1 = d1[k1] > Ti;
    float u1 = (p1 ? E1i : E2i) * (p1 ? d1[k1] : d2[k1]);
    u1 = (byt & (1u << k1)) ? u1 : 0.f;
    rs += u0 + u1;
    A.p[tp] = pkbf(u0, u1);
  }
  return A.v;
}

template <int F, int OUTM>
__global__ __launch_bounds__(256, 2) void k_agg_mfma(
    const uint4* __restrict__ pk, const float* __restrict__ Tt,
    const float* __restrict__ E1, const float* __restrict__ E2,
    const float* __restrict__ D1, const float* __restrict__ D2,
    const ull_t* __restrict__ mask, ushort_t* __restrict__ pkOut) {
  constexpr int CT = F / 16;
  constexpr int KSO = (H4 * F) / 32;
  constexpr int OPL = NN * H4 * F;
  __shared__ float red[2 * 32 * F];
  __shared__ float rsred[32 * 4];
  int t = threadIdx.x;
  int w = t >> 6, lane = t & 63;
  int q = lane >> 4, nn = lane & 15;
  int hd = blockIdx.y;
  int rowBase = blockIdx.x * 32;
  int jBase = w * (NN / 4);
  int ia0 = rowBase + nn, ia1 = rowBase + 16 + nn;
  float E1i0 = E1[hd * NN + ia0], E2i0 = E2[hd * NN + ia0], Ti0 = Tt[hd * NN + ia0];
  float E1i1 = E1[hd * NN + ia1], E2i1 = E2[hd * NN + ia1], Ti1 = Tt[hd * NN + ia1];
  const ull_t* mk0p = mask + (size_t)ia0 * 64;
  const ull_t* mk1p = mask + (size_t)ia1 * 64;
  const float* d1h = D1 + hd * NN;
  const float* d2h = D2 + hd * NN;

  f32x4 acc[2][CT];
#pragma unroll
  for (int rt = 0; rt < 2; ++rt)
#pragma unroll
    for (int cc = 0; cc < CT; ++cc)
#pragma unroll
      for (int k = 0; k < 4; ++k) acc[rt][cc][k] = 0.f;
  float rs0 = 0.f, rs1 = 0.f;

  for (int jc = 0; jc < NN / 4 / 64; ++jc) {
    int j0 = jBase + jc * 64;
    int ks0 = j0 >> 5;
    uint4 bv[2][CT];
#pragma unroll
    for (int s = 0; s < 2; ++s)
#pragma unroll
      for (int cc = 0; cc < CT; ++cc)
        bv[s][cc] = pk[(size_t)((hd * CT + cc) * (NN / 32) + ks0 + s) * 64 + lane];
    ull_t mk0 = mk0p[j0 >> 6], mk1 = mk1p[j0 >> 6];
    float4 d1a = *(const float4*)&d1h[j0 + q * 8];
    float4 d1b = *(const float4*)&d1h[j0 + q * 8 + 4];
    float4 d2a = *(const float4*)&d2h[j0 + q * 8];
    float4 d2b = *(const float4*)&d2h[j0 + q * 8 + 4];
    float4 d1c = *(const float4*)&d1h[j0 + 32 + q * 8];
    float4 d1d = *(const float4*)&d1h[j0 + 32 + q * 8 + 4];
    float4 d2c = *(const float4*)&d2h[j0 + 32 + q * 8];
    float4 d2d = *(const float4*)&d2h[j0 + 32 + q * 8 + 4];
    s16x8 a00 = build_af(E1i0, E2i0, Ti0, (unsigned)(mk0 >> (q * 8)) & 0xffu, d1a, d1b, d2a, d2b, rs0);
    s16x8 a01 = build_af(E1i0, E2i0, Ti0, (unsigned)(mk0 >> (32 + q * 8)) & 0xffu, d1c, d1d, d2c, d2d, rs0);
    s16x8 a10 = build_af(E1i1, E2i1, Ti1, (unsigned)(mk1 >> (q * 8)) & 0xffu, d1a, d1b, d2a, d2b, rs1);
    s16x8 a11 = build_af(E1i1, E2i1, Ti1, (unsigned)(mk1 >> (32 + q * 8)) & 0xffu, d1c, d1d, d2c, d2d, rs1);
#pragma unroll
    for (int cc = 0; cc < CT; ++cc)
      acc[0][cc] = __builtin_amdgcn_mfma_f32_16x16x32_bf16(a00, as_s16x8(bv[0][cc]), acc[0][cc], 0, 0, 0);
#pragma unroll
    for (int cc = 0; cc < CT; ++cc)
      acc[0][cc] = __builtin_amdgcn_mfma_f32_16x16x32_bf16(a01, as_s16x8(bv[1][cc]), acc[0][cc], 0, 0, 0);
#pragma unroll
    for (int cc = 0; cc < CT; ++cc)
      acc[1][cc] = __builtin_amdgcn_mfma_f32_16x16x32_bf16(a10, as_s16x8(bv[0][cc]), acc[1][cc], 0, 0, 0);
#pragma unroll
    for (int cc = 0; cc < CT; ++cc)
      acc[1][cc] = __builtin_amdgcn_mfma_f32_16x16x32_bf16(a11, as_s16x8(bv[1][cc]), acc[1][cc], 0, 0, 0);
  }

  // rs: reduce across q-quads, stash per wave
  rs0 += __shfl_xor(rs0, 16, 64); rs0 += __shfl_xor(rs0, 32, 64);
  rs1 += __shfl_xor(rs1, 16, 64); rs1 += __shfl_xor(rs1, 32, 64);
  if (q == 0) {
    rsred[nn * 4 + w] = rs0;
    rsred[(16 + nn) * 4 + w] = rs1;
  }

  // acc: 2-barrier cross-wave reduce
#define IDX(rt, cc, reg) ((rt * 16 + q * 4 + reg) * F + cc * 16 + nn)
  if (w == 1 || w == 3) {
    int base = (w >> 1) * 32 * F;
#pragma unroll
    for (int rt = 0; rt < 2; ++rt)
#pragma unroll
      for (int cc = 0; cc < CT; ++cc)
#pragma unroll
        for (int reg = 0; reg < 4; ++reg) red[base + IDX(rt, cc, reg)] = acc[rt][cc][reg];
  }
  __syncthreads();
  if (w == 0 || w == 2) {
    int base = (w >> 1) * 32 * F;
#pragma unroll
    for (int rt = 0; rt < 2; ++rt)
#pragma unroll
      for (int cc = 0; cc < CT; ++cc)
#pragma unroll
        for (int reg = 0; reg < 4; ++reg) acc[rt][cc][reg] += red[base + IDX(rt, cc, reg)];
  }
  if (w == 2) {
#pragma unroll
    for (int rt = 0; rt < 2; ++rt)
#pragma unroll
      for (int cc = 0; cc < CT; ++cc)
#pragma unroll
        for (int reg = 0; reg < 4; ++reg) red[32 * F + IDX(rt, cc, reg)] = acc[rt][cc][reg];
  }
  __syncthreads();
  if (w == 0) {
    float rinv[2][4];
#pragma unroll
    for (int rt = 0; rt < 2; ++rt)
#pragma unroll
      for (int reg = 0; reg < 4; ++reg) {
        int row = rt * 16 + q * 4 + reg;
        float4 rv = *(float4*)&rsred[row * 4];
        float s = (rv.x + rv.y) + (rv.z + rv.w);
        rinv[rt][reg] = (s > 0.f) ? 1.f / s : 0.f;
      }
#pragma unroll
    for (int rt = 0; rt < 2; ++rt)
#pragma unroll
      for (int cc = 0; cc < CT; ++cc)
#pragma unroll
        for (int reg = 0; reg < 4; ++reg) {
          float v = (acc[rt][cc][reg] + red[32 * F + IDX(rt, cc, reg)]) * rinv[rt][reg];
          int gi = rowBase + rt * 16 + q * 4 + reg;
          int c = hd * F + cc * 16 + nn;
          int mt = gi >> 4, rowin = gi & 15;
          int ks = c >> 5, qp = (c >> 3) & 3, u = c & 7;
          size_t idx = (((size_t)mt * KSO + ks) * 64 + qp * 16 + rowin) * 8 + u;
          ushort_t hi = f2bf(v);
          pkOut[idx] = hi;
          if (OUTM == 1) pkOut[OPL + idx] = f2bf(v - bf2f(hi));
        }
  }
#undef IDX
}

// ---------------- y1 = pkX1(bf16) @ lw1(hi/lo) + lb1, MFMA, K-split x2 ----------------
__global__ __launch_bounds__(256) void k_mm2(const uint4* __restrict__ pkX,
                                             const uint4* __restrict__ pkW,
                                             const float* __restrict__ bias,
                                             float* __restrict__ y) {
  constexpr int WPL4 = 4 * 16 * 64;
  __shared__ float red[2 * 16 * 64];
  int t = threadIdx.x;
  int w = t >> 6, lane = t & 63;
  int q = lane >> 4, nn = lane & 15;
  int mt = blockIdx.x * 2 + (w & 1);
  int kh = w >> 1;
  f32x4 acc[4];
#pragma unroll
  for (int c = 0; c < 4; ++c)
#pragma unroll
    for (int k = 0; k < 4; ++k) acc[c][k] = 0.f;
#pragma unroll
  for (int k8 = 0; k8 < 8; ++k8) {
    int ks = kh * 8 + k8;
    uint4 a = pkX[(mt * 16 + ks) * 64 + lane];
#pragma unroll
    for (int c = 0; c < 4; ++c) {
      uint4 bh = pkW[(c * 16 + ks) * 64 + lane];
      uint4 bl = pkW[WPL4 + (c * 16 + ks) * 64 + lane];
      acc[c] = __builtin_amdgcn_mfma_f32_16x16x32_bf16(as_s16x8(a), as_s16x8(bh), acc[c], 0, 0, 0);
      acc[c] = __builtin_amdgcn_mfma_f32_16x16x32_bf16(as_s16x8(a), as_s16x8(bl), acc[c], 0, 0, 0);
    }
  }
  int base = (w & 1) * 1024;
  if (kh == 1) {
#pragma unroll
    for (int c = 0; c < 4; ++c)
#pragma unroll
      for (int reg = 0; reg < 4; ++reg)
        red[base + (q * 4 + reg) * 64 + c * 16 + nn] = acc[c][reg];
  }
  __syncthreads();
  if (kh == 0) {
#pragma unroll
    for (int c = 0; c < 4; ++c)
#pragma unroll
      for (int reg = 0; reg < 4; ++reg) {
        float v = acc[c][reg] + red[base + (q * 4 + reg) * 64 + c * 16 + nn] + bias[c * 16 + nn];
        y[(size_t)(mt * 16 + q * 4 + reg) * 64 + c * 16 + nn] = v;
      }
  }
}

// ---------------- y2 = pkX3(hi/lo) @ lw2(hi/lo) + lb2, MFMA ----------------
__global__ __launch_bounds__(256) void k_mm4(const uint4* __restrict__ pkX,
                                             const uint4* __restrict__ pkW,
                                             const float* __restrict__ bias,
                                             float* __restrict__ y) {
  constexpr int XPL4 = 256 * 4 * 64;
  constexpr int WPL4 = 1 * 4 * 64;
  int t = threadIdx.x;
  int w = t >> 6, lane = t & 63;
  int q = lane >> 4, nn = lane & 15;
  int mt = blockIdx.x * 4 + w;
  f32x4 acc;
#pragma unroll
  for (int k = 0; k < 4; ++k) acc[k] = 0.f;
#pragma unroll
  for (int ks = 0; ks < 4; ++ks) {
    uint4 ah = pkX[(mt * 4 + ks) * 64 + lane];
    uint4 al = pkX[XPL4 + (mt * 4 + ks) * 64 + lane];
    uint4 bh = pkW[ks * 64 + lane];
    uint4 bl = pkW[WPL4 + ks * 64 + lane];
    acc = __builtin_amdgcn_mfma_f32_16x16x32_bf16(as_s16x8(ah), as_s16x8(bh), acc, 0, 0, 0);
    acc = __builtin_amdgcn_mfma_f32_16x16x32_bf16(as_s16x8(ah), as_s16x8(bl), acc, 0, 0, 0);
    acc = __builtin_amdgcn_mfma_f32_16x16x32_bf16(as_s16x8(al), as_s16x8(bh), acc, 0, 0, 0);
  }
  float b = bias[nn];
#pragma unroll
  for (int reg = 0; reg < 4; ++reg)
    y[(size_t)(mt * 16 + q * 4 + reg) * 16 + nn] = acc[reg] + b;
}

// ---------------- fused per-column BN stats + BN + ELU ----------------
__global__ __launch_bounds__(256) void k_bn_col(const float* __restrict__ y,
                                                const float* __restrict__ gamma,
                                                const float* __restrict__ beta,
                                                float* __restrict__ o, int C) {
  int c = blockIdx.x, tid = threadIdx.x;
  float s = 0.f, s2 = 0.f;
  for (int r = tid; r < NN; r += 256) {
    float v = y[(size_t)r * C + c];
    s += v;
    s2 += v * v;
  }
  __shared__ float sh[256], sh2[256];
  __shared__ float smu, srs;
  sh[tid] = s; sh2[tid] = s2;
  __syncthreads();
  for (int off = 128; off; off >>= 1) {
    if (tid < off) { sh[tid] += sh[tid + off]; sh2[tid] += sh2[tid + off]; }
    __syncthreads();
  }
  if (tid == 0) {
    float mu = sh[0] * (1.f / NN);
    float var = sh2[0] * (1.f / NN) - mu * mu;
    smu = mu;
    srs = rsqrtf(fmaxf(var, 0.f) + 1e-5f);
  }
  __syncthreads();
  float mu = smu, rstd = srs, g = gamma[c], b = beta[c];
  for (int r = tid; r < NN; r += 256) {
    float v = (y[(size_t)r * C + c] - mu) * rstd * g + b;
    v = v > 0.f ? v : (__expf(v) - 1.f);
    o[(size_t)r * C + c] = v;
  }
}

extern "C" void kernel_launch(void* const* d_in, const int* in_sizes, int n_in,
                              void* d_out, int out_size, void* d_ws, size_t ws_size,
                              hipStream_t stream) {
  (void)in_sizes; (void)n_in; (void)out_size; (void)ws_size;
  const float* x   = (const float*)d_in[0];
  const int*   adj = (const int*)d_in[1];
  const float* W1  = (const float*)d_in[2];
  const float* a1s = (const float*)d_in[3];
  const float* a1d = (const float*)d_in[4];
  const float* lw1 = (const float*)d_in[5];
  const float* lb1 = (const float*)d_in[6];
  const float* g1  = (const float*)d_in[7];
  const float* be1 = (const float*)d_in[8];
  const float* W2  = (const float*)d_in[9];
  const float* a2s = (const float*)d_in[10];
  const float* a2d = (const float*)d_in[11];
  const float* lw2 = (const float*)d_in[12];
  const float* lb2 = (const float*)d_in[13];
  const float* g2  = (const float*)d_in[14];
  const float* be2 = (const float*)d_in[15];
  float* out = (float*)d_out;

  // ---- workspace: LINEAR layout, no overlays (~38 MB of >=268 MB) ----
  char* w = (char*)d_ws;
  const size_t MB = 1u << 20;
  ull_t*    mask  = (ull_t*)(w + 0);              // 2 MB
  ushort_t* pkA   = (ushort_t*)(w + 2 * MB);      // 8 MB
  ushort_t* pkW1  = (ushort_t*)(w + 10 * MB);     // 1 MB
  float*    h1    = (float*)(w + 11 * MB);        // 8 MB
  ushort_t* pk1   = (ushort_t*)(w + 19 * MB);     // 4 MB
  float*    T1    = (float*)(w + 23 * MB);        // 5 x 64 KB
  float*    E1a   = T1 + 16384;
  float*    E2a   = E1a + 16384;
  float*    D1a   = E2a + 16384;
  float*    D2a   = D1a + 16384;
  ushort_t* pkX1  = (ushort_t*)(w + 24 * MB);     // 4 MB
  ushort_t* pkLW1 = (ushort_t*)(w + 28 * MB);     // 128 KB
  float*    y1    = (float*)(w + 29 * MB);        // 1 MB
  float*    x2    = (float*)(w + 30 * MB);        // 1 MB
  float*    h2    = (float*)(w + 31 * MB);        // 2 MB
  ushort_t* pk2   = (ushort_t*)(w + 33 * MB);     // 1 MB
  float*    T2    = (float*)(w + 34 * MB);        // 5 x 64 KB
  float*    E1b   = T2 + 16384;
  float*    E2b   = E1b + 16384;
  float*    D1b   = E2b + 16384;
  float*    D2b   = D1b + 16384;
  ushort_t* pkX3  = (ushort_t*)(w + 35 * MB);     // 2 MB
  ushort_t* pkLW2 = (ushort_t*)(w + 37 * MB);     // 8 KB
  float*    y2    = (float*)(w + 37 * MB + 131072);  // 256 KB

  k_mask<<<NN, 256, 0, stream>>>(adj, mask);
  k_packP<<<1169, 256, 0, stream>>>(x, W1, lw1, lw2, pkA, pkW1, pkLW1, pkLW2);

  // ---- layer 1 GAT ----
  k_mm1<<<dim3(64, 4), 256, 0, stream>>>((const uint4*)pkA, (const uint4*)pkW1, h1);
  k_pack<128, 256><<<dim3(NN / 32, H4), 256, 0, stream>>>(h1, pk1);
  k_scores<128><<<(NN * H4) / 256, 256, 0, stream>>>(h1, a1s, a1d, T1, E1a, E2a, D1a, D2a);
  k_agg_mfma<128, 0><<<dim3(NN / 32, H4), 256, 0, stream>>>((const uint4*)pk1, T1, E1a, E2a,
                                                            D1a, D2a, mask, pkX1);

  // ---- linear + BN + ELU ----
  k_mm2<<<128, 256, 0, stream>>>((const uint4*)pkX1, (const uint4*)pkLW1, lb1, y1);
  k_bn_col<<<64, 256, 0, stream>>>(y1, g1, be1, x2, 64);

  // ---- layer 2 GAT ----
  k_gemm<<<dim3(2, 64), 256, 0, stream>>>(x2, W2, nullptr, h2, NN, 64, 128);
  k_pack<32, 128><<<dim3(NN / 32, H4), 128, 0, stream>>>(h2, pk2);
  k_scores<32><<<(NN * H4) / 256, 256, 0, stream>>>(h2, a2s, a2d, T2, E1b, E2b, D1b, D2b);
  k_agg_mfma<32, 1><<<dim3(NN / 32, H4), 256, 0, stream>>>((const uint4*)pk2, T2, E1b, E2b,
                                                           D1b, D2b, mask, pkX3);

  // ---- final linear + BN + ELU ----
  k_mm4<<<64, 256, 0, stream>>>((const uint4*)pkX3, (const uint4*)pkLW2, lb2, y2);
  k_bn_col<<<16, 256, 0, stream>>>(y2, g2, be2, out, 16);
}